// Round 3
// baseline (235.727 us; speedup 1.0000x reference)
//
#include <hip/hip_runtime.h>
#include <cmath>

#define NN 8192
#define DD 512
#define NSRC 8
#define PSW 8                  // ps partials per row = 8 column groups
#define COFF 100.0f            // fixed softmax offset

typedef __bf16 bf16x8 __attribute__((ext_vector_type(8)));
typedef float  f32x4  __attribute__((ext_vector_type(4)));

__device__ __forceinline__ unsigned short f2bf(float f) {
    unsigned u = __float_as_uint(f);
    u += 0x7fffu + ((u >> 16) & 1u);
    return (unsigned short)(u >> 16);
}

// ---------------------------------------------------------------------------
// R3: ONE persistent kernel (256 blocks = 1/CU, co-residency forced by the
// 128 KiB LDS allocation) doing cast -> grid-sync -> 8-phase GEMM (R2 phase
// machine verbatim) -> panel-sync -> fused finalize. Plus one small memset
// node zeroing control counters + Tsum + counts. 2 graph nodes total (was 5).
//
// Cross-XCD coherence: plain-store producers do {__syncthreads (drains vmcnt),
// __threadfence (buffer_wbl2), atomicAdd arrive}; consumers observe the
// counter then {__threadfence (buffer_inv), __syncthreads}. Atomic chains
// (ws_acc -> done) are fenced between RMWs. Graph replays re-run the memset,
// so counters are re-zeroed each timed iteration; rocprof kernel-only replay
// leaves counters saturated => spins exit immediately, out-write is gated on
// the exact transition o==255 so it is never re-triggered with stale data.
// ---------------------------------------------------------------------------
__global__ __launch_bounds__(512, 2) void k_fused(
    const float* __restrict__ img, const float* __restrict__ txt,
    const int* __restrict__ labels, const float* __restrict__ scale_p,
    unsigned short* __restrict__ imgB, unsigned short* __restrict__ txtB,
    unsigned* __restrict__ sync_cnt, unsigned* __restrict__ panel_cnt,
    unsigned* __restrict__ done_cnt, float* __restrict__ ws_acc,
    float* __restrict__ Tsum, int* __restrict__ counts,
    float* __restrict__ ps, float* __restrict__ out)
{
    __shared__ uint4 lds[8192];            // 128 KiB
    const int tid  = threadIdx.x;
    const int lane = tid & 63;
    const int w    = tid >> 6;
    const int wr   = w >> 2;
    const int wc   = w & 3;
    const int lq   = lane >> 4;
    const int ln   = lane & 15;
    // XCD-aware bijective mapping (256 blocks, 8 XCDs)
    const int c    = blockIdx.x & 7;
    const int l    = blockIdx.x >> 3;
    const int by   = c * 4 + (l >> 3);     // row panel 0..31
    const int bcg  = l & 7;                // column group 0..7
    const int row0    = by * 256;
    const int colBase = bcg * 1024;

    // ======================= stage 1: cast (all blocks) ====================
    {
        const size_t half = (size_t)NN * DD / 8;   // 8-elem chunks per matrix
#pragma unroll
        for (int cch = 0; cch < 8; cch++) {
            const size_t gid = (size_t)blockIdx.x * 4096 + (size_t)cch * 512 + tid;
            const float* src = (gid < half) ? img : txt;
            unsigned short* dst = (gid < half) ? imgB : txtB;
            const size_t off = ((gid < half) ? gid : gid - half) * 8;
            const float4 v0 = *(const float4*)(src + off);
            const float4 v1 = *(const float4*)(src + off + 4);
            union { unsigned short s[8]; uint4 v; } o;
            o.s[0] = f2bf(v0.x); o.s[1] = f2bf(v0.y); o.s[2] = f2bf(v0.z); o.s[3] = f2bf(v0.w);
            o.s[4] = f2bf(v1.x); o.s[5] = f2bf(v1.y); o.s[6] = f2bf(v1.z); o.s[7] = f2bf(v1.w);
            *(uint4*)(dst + off) = o.v;
        }
    }
    // ---- stage 1b: per-source text sums (blocks 0..127, 64 rows each) ----
    if (blockIdx.x < 128) {
        const int r0 = blockIdx.x * 64;
        float accs[NSRC];
#pragma unroll
        for (int s = 0; s < NSRC; s++) accs[s] = 0.f;
#pragma unroll 8
        for (int j = 0; j < 64; j++) {
            const int lab = labels[r0 + j];
            const float v = txt[(size_t)(r0 + j) * DD + tid];
#pragma unroll
            for (int s = 0; s < NSRC; s++)
                accs[s] += (lab == s) ? v : 0.f;
        }
#pragma unroll
        for (int s = 0; s < NSRC; s++)
            atomicAdd(&Tsum[s * DD + tid], accs[s]);
        if (tid < 64) atomicAdd(&counts[labels[r0 + tid]], 1);
    }

    // ======================= grid-wide sync ================================
    __syncthreads();                       // drains all stage-1 stores (vmcnt)
    if (tid == 0) {
        __threadfence();                   // release: wbL2 -> data at L3/HBM
        atomicAdd(sync_cnt, 1u);
        while (atomicAdd(sync_cnt, 0u) < 256u) __builtin_amdgcn_s_sleep(8);
        __threadfence();                   // acquire: inv stale L1/L2 lines
    }
    __syncthreads();

    // ======================= stage 2: GEMM (R2 verbatim) ===================
    const float scale = scale_p[0];
    const int st_r  = tid >> 3;
    const int st_kc = (tid & 7) ^ (st_r & 7);
    const int xsw   = ln & 7;

    int rowA[2][4], colB[2][2];
#pragma unroll
    for (int ih = 0; ih < 2; ih++)
#pragma unroll
        for (int ii = 0; ii < 4; ii++)
            rowA[ih][ii] = (wr * 128 + ih * 64 + ii * 16 + ln) * 8;
#pragma unroll
    for (int jh = 0; jh < 2; jh++)
#pragma unroll
        for (int jj = 0; jj < 2; jj++)
            colB[jh][jj] = (wc * 64 + jh * 32 + jj * 16 + ln) * 8;

#define SA(BUF, Q, T)                                                          \
    { const unsigned short* g = imgB + (size_t)(row0 + (Q) * 64 + st_r) * DD   \
          + (((T) & 7) << 6) + (st_kc << 3);                                   \
      __builtin_amdgcn_global_load_lds(                                        \
          (const __attribute__((address_space(1))) void*)g,                    \
          (__attribute__((address_space(3))) void*)                            \
              &lds[(BUF) * 4096 + (Q) * 512 + tid], 16, 0, 0); }
#define SB(BUF, Q, T)                                                          \
    { const unsigned short* g = txtB                                           \
          + (size_t)(colBase + ((((T) >> 3) & 3) << 8) + (Q) * 64 + st_r) * DD \
          + (((T) & 7) << 6) + (st_kc << 3);                                   \
      __builtin_amdgcn_global_load_lds(                                        \
          (const __attribute__((address_space(1))) void*)g,                    \
          (__attribute__((address_space(3))) void*)                            \
              &lds[(BUF) * 4096 + 2048 + (Q) * 512 + tid], 16, 0, 0); }

#define PHASE_(BUF, IH, JH, RA, STG, VM)                                       \
    do {                                                                       \
        if (RA) {                                                              \
            _Pragma("unroll") for (int ii = 0; ii < 4; ii++) {                 \
                _Pragma("unroll") for (int ks = 0; ks < 2; ks++) {             \
                    af[ii][ks] = *reinterpret_cast<const bf16x8*>(             \
                        &lds[(BUF) * 4096 + rowA[IH][ii]                       \
                             + (((ks << 2) + lq) ^ xsw)]);                     \
                }                                                              \
            }                                                                  \
        }                                                                      \
        bf16x8 bf[2][2];                                                       \
        _Pragma("unroll") for (int jj = 0; jj < 2; jj++) {                     \
            _Pragma("unroll") for (int ks = 0; ks < 2; ks++) {                 \
                bf[jj][ks] = *reinterpret_cast<const bf16x8*>(                 \
                    &lds[(BUF) * 4096 + 2048 + colB[JH][jj]                    \
                         + (((ks << 2) + lq) ^ xsw)]);                         \
            }                                                                  \
        }                                                                      \
        STG;                                                                   \
        __builtin_amdgcn_s_barrier();                                          \
        asm volatile("s_waitcnt lgkmcnt(0)" ::: "memory");                     \
        __builtin_amdgcn_sched_barrier(0);                                     \
        __builtin_amdgcn_s_setprio(1);                                         \
        _Pragma("unroll") for (int ks = 0; ks < 2; ks++) {                     \
            _Pragma("unroll") for (int ii = 0; ii < 4; ii++) {                 \
                _Pragma("unroll") for (int jj = 0; jj < 2; jj++) {             \
                    acc[(IH) * 4 + ii][(JH) * 2 + jj] =                        \
                        __builtin_amdgcn_mfma_f32_16x16x32_bf16(               \
                            af[ii][ks], bf[jj][ks],                            \
                            acc[(IH) * 4 + ii][(JH) * 2 + jj], 0, 0, 0);       \
                }                                                              \
            }                                                                  \
        }                                                                      \
        __builtin_amdgcn_s_setprio(0);                                         \
        if (VM) { asm volatile("s_waitcnt vmcnt(2)" ::: "memory"); }           \
        __builtin_amdgcn_s_barrier();                                          \
    } while (0)

    // ---- prologue: tile 0 fully + tile 1 Aq0,Aq2 ----
#pragma unroll
    for (int q = 0; q < 4; q++) SA(0, q, 0);
#pragma unroll
    for (int q = 0; q < 4; q++) SB(0, q, 0);
    SA(1, 0, 1); SA(1, 2, 1);
    asm volatile("s_waitcnt vmcnt(2)" ::: "memory");
    __builtin_amdgcn_s_barrier();

    f32x4 acc[8][4];
    f32x4 s_run[8];
#pragma unroll
    for (int i = 0; i < 8; i++) {
        s_run[i] = (f32x4){0.f, 0.f, 0.f, 0.f};
#pragma unroll
        for (int j = 0; j < 4; j++) acc[i][j] = (f32x4){0.f, 0.f, 0.f, 0.f};
    }
    bf16x8 af[4][2];

#pragma unroll 1
    for (int v0 = 0; v0 < 32; v0 += 2) {
        PHASE_(0, 0, 0, 1, SA(1, 1, v0 + 1); SA(1, 3, v0 + 1), 0);
        PHASE_(0, 0, 1, 0, SB(1, 0, v0 + 1); SB(1, 1, v0 + 1), 0);
        PHASE_(0, 1, 0, 1, SB(1, 2, v0 + 1); SB(1, 3, v0 + 1), 0);
        PHASE_(0, 1, 1, 0, SA(0, 0, v0 + 2); SA(0, 2, v0 + 2), 1);
        PHASE_(1, 0, 0, 1, SA(0, 1, v0 + 2); SA(0, 3, v0 + 2), 0);
        PHASE_(1, 0, 1, 0, SB(0, 0, v0 + 2); SB(0, 1, v0 + 2), 0);
        PHASE_(1, 1, 0, 1, SB(0, 2, v0 + 2); SB(0, 3, v0 + 2), 0);
        PHASE_(1, 1, 1, 0, SA(1, 0, v0 + 3); SA(1, 2, v0 + 3), 1);
        if ((v0 & 6) == 6) {
            // ct boundary: register-only exp flush (no barrier, no loads)
#pragma unroll
            for (int i = 0; i < 8; i++) {
#pragma unroll
                for (int rg = 0; rg < 4; rg++) {
                    float es = s_run[i][rg];
#pragma unroll
                    for (int j = 0; j < 4; j++)
                        es += __expf(fmaf(acc[i][j][rg], scale, -COFF));
                    s_run[i][rg] = es;
                }
#pragma unroll
                for (int j = 0; j < 4; j++)
                    acc[i][j] = (f32x4){0.f, 0.f, 0.f, 0.f};
            }
        }
    }

    asm volatile("s_waitcnt vmcnt(0)" ::: "memory");
    __syncthreads();

    // ---- GEMM epilogue: reduce s_run across ln, fold 4 wc-waves via LDS ----
    float* fred = (float*)lds;                 // 4 KB
#pragma unroll
    for (int i = 0; i < 8; i++) {
#pragma unroll
        for (int rg = 0; rg < 4; rg++) {
            float es = s_run[i][rg];
#pragma unroll
            for (int off = 8; off; off >>= 1) es += __shfl_xor(es, off);
            if (ln == 0)
                fred[(wr * 128 + i * 16 + lq * 4 + rg) * 4 + wc] = es;
        }
    }
    __syncthreads();
    if (tid < 256) {
        const float tot = fred[tid * 4] + fred[tid * 4 + 1]
                        + fred[tid * 4 + 2] + fred[tid * 4 + 3];
        ps[(size_t)(row0 + tid) * PSW + bcg] = tot;
    }
#undef SA
#undef SB
#undef PHASE_

    // ======================= stage 3: panel sync + finalize ================
    __syncthreads();                       // drains ps stores
    if (tid == 0) {
        __threadfence();                   // release ps
        atomicAdd(&panel_cnt[by], 1u);
        while (atomicAdd(&panel_cnt[by], 0u) < 8u) __builtin_amdgcn_s_sleep(8);
        __threadfence();                   // acquire ps/Tsum/counts
    }
    __syncthreads();

    // each block finalizes its own 32-row slice of the panel
    float local = 0.f;
    const int rowF = row0 + bcg * 32 + w * 4;
#pragma unroll
    for (int it = 0; it < 4; it++) {
        const int i = rowF + it;
        const int lab = labels[i];
        float ds = 0.f, dt = 0.f;
        const float* ip = img + (size_t)i * DD;
        const float* tp = txt + (size_t)i * DD;
        const float* sp = Tsum + lab * DD;
#pragma unroll
        for (int k = lane; k < DD; k += 64) {
            const float a = ip[k];
            ds = fmaf(a, tp[k], ds);
            dt = fmaf(a, sp[k], dt);
        }
        float es = (lane < PSW) ? ps[(size_t)i * PSW + lane] : 0.f;
#pragma unroll
        for (int off = 32; off; off >>= 1) {
            ds += __shfl_xor(ds, off);
            dt += __shfl_xor(dt, off);
            es += __shfl_xor(es, off);
        }
        if (lane == 0) {
            const float lse = COFF + __logf(es);
            const int cnt = counts[lab] - 1;
            if (cnt > 0) {
                const float row_sum = scale * (dt - ds) - (float)cnt * lse;
                local += row_sum / (float)cnt;
            }
        }
    }
    float* red = (float*)lds + 2048;       // 8 KB offset, past fred
    if (lane == 0) red[w] = local;
    __syncthreads();
    if (tid == 0) {
        float tot = 0.f;
#pragma unroll
        for (int i = 0; i < 8; i++) tot += red[i];
        atomicAdd(ws_acc, tot);
        __threadfence();                   // order ws_acc before done
        const unsigned o = atomicAdd(done_cnt, 1u);
        if (o == 255u) {
            __threadfence();
            const float v = atomicAdd(ws_acc, 0.0f);   // coherent read
            out[0] = -v / (float)NN;
        }
    }
}

// ---------------------------------------------------------------------------
extern "C" void kernel_launch(void* const* d_in, const int* in_sizes, int n_in,
                              void* d_out, int out_size, void* d_ws, size_t ws_size,
                              hipStream_t stream)
{
    const float* img     = (const float*)d_in[0];
    const float* txt     = (const float*)d_in[1];
    const float* scale_p = (const float*)d_in[2];
    const int*   labels  = (const int*)d_in[3];
    float* out = (float*)d_out;

    char* ws = (char*)d_ws;
    // zeroed control region: [sync(4) done(4) ws_acc(4) pad.. panel(64..192)
    //                         Tsum(256..16640) counts(16640..16672)]
    unsigned* sync_cnt  = (unsigned*)(ws + 0);
    unsigned* done_cnt  = (unsigned*)(ws + 4);
    float*    ws_acc    = (float*)(ws + 8);
    unsigned* panel_cnt = (unsigned*)(ws + 64);
    float*    Tsum      = (float*)(ws + 256);
    int*      counts    = (int*)(ws + 256 + NSRC * DD * 4);
    float*    ps        = (float*)(ws + 32768);                   // 256 KB
    unsigned short* imgB = (unsigned short*)(ws + 2 * 1024 * 1024);   // 8 MB
    unsigned short* txtB = (unsigned short*)(ws + 10 * 1024 * 1024);  // 8 MB

    hipMemsetAsync(ws, 0, 256 + NSRC * DD * 4 + 64, stream);

    k_fused<<<256, 512, 0, stream>>>(img, txt, labels, scale_p,
                                     imgB, txtB,
                                     sync_cnt, panel_cnt, done_cnt, ws_acc,
                                     Tsum, counts, ps, out);
}

// Round 4
// 168.779 us; speedup vs baseline: 1.3967x; 1.3967x over previous
//
#include <hip/hip_runtime.h>
#include <cmath>

#define NN 8192
#define DD 512
#define NSRC 8
#define PSW 8                  // ps partials per row = 8 column groups
#define COFF 100.0f            // fixed softmax offset

typedef __bf16 bf16x8 __attribute__((ext_vector_type(8)));
typedef float  f32x4  __attribute__((ext_vector_type(4)));

__device__ __forceinline__ unsigned short f2bf(float f) {
    unsigned u = __float_as_uint(f);
    u += 0x7fffu + ((u >> 16) & 1u);
    return (unsigned short)(u >> 16);
}

// ---------------------------------------------------------------------------
// Kernel A (= R2 k_prep): blocks 0..127 per-source text sums; blocks 128+
// cast fp32->bf16. Tsum/counts/out zeroed by hipMemsetAsync.
// ---------------------------------------------------------------------------
__global__ __launch_bounds__(256) void k_prep(
    const float* __restrict__ img, const float* __restrict__ txt,
    const int* __restrict__ labels,
    unsigned short* __restrict__ imgB, unsigned short* __restrict__ txtB,
    float* __restrict__ Tsum, int* __restrict__ counts)
{
    const int tid = threadIdx.x;
    if (blockIdx.x >= 128) {
        const size_t gid = (size_t)(blockIdx.x - 128) * 256 + tid;
        const size_t half = (size_t)NN * DD / 8;
        const float* src = (gid < half) ? img : txt;
        unsigned short* dst = (gid < half) ? imgB : txtB;
        const size_t off = ((gid < half) ? gid : gid - half) * 8;
        const float4 v0 = *(const float4*)(src + off);
        const float4 v1 = *(const float4*)(src + off + 4);
        union { unsigned short s[8]; uint4 v; } o;
        o.s[0] = f2bf(v0.x); o.s[1] = f2bf(v0.y); o.s[2] = f2bf(v0.z); o.s[3] = f2bf(v0.w);
        o.s[4] = f2bf(v1.x); o.s[5] = f2bf(v1.y); o.s[6] = f2bf(v1.z); o.s[7] = f2bf(v1.w);
        *(uint4*)(dst + off) = o.v;
        return;
    }
    __shared__ float Tacc[NSRC * DD];
    __shared__ int cacc[NSRC];
    const int d0 = 2 * tid;
#pragma unroll
    for (int s = 0; s < NSRC; s++) {
        Tacc[s * DD + d0] = 0.f;
        Tacc[s * DD + d0 + 1] = 0.f;
    }
    if (tid < NSRC) cacc[tid] = 0;
    __syncthreads();

    const int row0 = blockIdx.x * 64;
    if (tid < 64) atomicAdd(&cacc[labels[row0 + tid]], 1);

    for (int j = 0; j < 64; j++) {
        const int lab = labels[row0 + j];
        const float2 v = *(const float2*)(txt + (size_t)(row0 + j) * DD + d0);
        Tacc[lab * DD + d0]     += v.x;
        Tacc[lab * DD + d0 + 1] += v.y;
    }
    __syncthreads();
#pragma unroll
    for (int k = 0; k < NSRC * DD / 256; k++) {
        const int e = k * 256 + tid;
        atomicAdd(&Tsum[e], Tacc[e]);
    }
    if (tid < NSRC) atomicAdd(&counts[tid], cacc[tid]);
}

// ---------------------------------------------------------------------------
// Kernel B (R4): persistent 256-block 8-phase GEMM, R2 phase machine with a
// DEEPER stage schedule (S''). Waits (vmcnt(2) @ph4/ph8) and barriers are
// IDENTICAL to R2; only the issue phases of the global_load_lds moved:
//   ph1: A(t+1)q1,q3 + B(t+1)q0..q3  (6 loads)  [buf1 regions freed prev ph8]
//   ph3: A(t+2)q0,q2                 (2 loads)  [buf0 Aq0q2 freed after ph2]
//   ph5: A(t+2)q1,q3 + B(t+2)q0..q3  (6 loads)  [buf0 regions freed after ph4]
//   ph7: A(t+3)q0,q2                 (2 loads)  [buf1 Aq0q2 freed after ph6]
// Outstanding at W4: prevph7(2)+ph1(6)+ph3(2)=10 -> vmcnt(2) drains exactly
// tile t+1's 8; at W8: ph3(2)+ph5(6)+ph7(2)=10 -> drains exactly tile t+2's 8.
// Every load now has >=3 phases of issue-to-wait cover (was 1-1.5).
// ---------------------------------------------------------------------------
__global__ __launch_bounds__(512, 2) void k_lse_mfma256(
    const unsigned short* __restrict__ imgB, const unsigned short* __restrict__ txtB,
    const float* __restrict__ scale_p, float* __restrict__ ps)
{
    __shared__ uint4 lds[8192];            // 128 KiB
    const float scale = scale_p[0];
    const int tid  = threadIdx.x;
    const int lane = tid & 63;
    const int w    = tid >> 6;
    const int wr   = w >> 2;
    const int wc   = w & 3;
    const int lq   = lane >> 4;
    const int ln   = lane & 15;
    const int c    = blockIdx.x & 7;       // XCD (round-robin dispatch)
    const int l    = blockIdx.x >> 3;
    const int by   = c * 4 + (l >> 3);     // row panel 0..31
    const int bcg  = l & 7;                // column group 0..7
    const int row0    = by * 256;
    const int colBase = bcg * 1024;

    const int st_r  = tid >> 3;
    const int st_kc = (tid & 7) ^ (st_r & 7);
    const int xsw   = ln & 7;

    int rowA[2][4], colB[2][2];
#pragma unroll
    for (int ih = 0; ih < 2; ih++)
#pragma unroll
        for (int ii = 0; ii < 4; ii++)
            rowA[ih][ii] = (wr * 128 + ih * 64 + ii * 16 + ln) * 8;
#pragma unroll
    for (int jh = 0; jh < 2; jh++)
#pragma unroll
        for (int jj = 0; jj < 2; jj++)
            colB[jh][jj] = (wc * 64 + jh * 32 + jj * 16 + ln) * 8;

#define SA(BUF, Q, T)                                                          \
    { const unsigned short* g = imgB + (size_t)(row0 + (Q) * 64 + st_r) * DD   \
          + (((T) & 7) << 6) + (st_kc << 3);                                   \
      __builtin_amdgcn_global_load_lds(                                        \
          (const __attribute__((address_space(1))) void*)g,                    \
          (__attribute__((address_space(3))) void*)                            \
              &lds[(BUF) * 4096 + (Q) * 512 + tid], 16, 0, 0); }
#define SB(BUF, Q, T)                                                          \
    { const unsigned short* g = txtB                                           \
          + (size_t)(colBase + ((((T) >> 3) & 3) << 8) + (Q) * 64 + st_r) * DD \
          + (((T) & 7) << 6) + (st_kc << 3);                                   \
      __builtin_amdgcn_global_load_lds(                                        \
          (const __attribute__((address_space(1))) void*)g,                    \
          (__attribute__((address_space(3))) void*)                            \
              &lds[(BUF) * 4096 + 2048 + (Q) * 512 + tid], 16, 0, 0); }

#define PHASE_(BUF, IH, JH, RA, STG, VM)                                       \
    do {                                                                       \
        if (RA) {                                                              \
            _Pragma("unroll") for (int ii = 0; ii < 4; ii++) {                 \
                _Pragma("unroll") for (int ks = 0; ks < 2; ks++) {             \
                    af[ii][ks] = *reinterpret_cast<const bf16x8*>(             \
                        &lds[(BUF) * 4096 + rowA[IH][ii]                       \
                             + (((ks << 2) + lq) ^ xsw)]);                     \
                }                                                              \
            }                                                                  \
        }                                                                      \
        bf16x8 bf[2][2];                                                       \
        _Pragma("unroll") for (int jj = 0; jj < 2; jj++) {                     \
            _Pragma("unroll") for (int ks = 0; ks < 2; ks++) {                 \
                bf[jj][ks] = *reinterpret_cast<const bf16x8*>(                 \
                    &lds[(BUF) * 4096 + 2048 + colB[JH][jj]                    \
                         + (((ks << 2) + lq) ^ xsw)]);                         \
            }                                                                  \
        }                                                                      \
        STG;                                                                   \
        __builtin_amdgcn_s_barrier();                                          \
        asm volatile("s_waitcnt lgkmcnt(0)" ::: "memory");                     \
        __builtin_amdgcn_sched_barrier(0);                                     \
        __builtin_amdgcn_s_setprio(1);                                         \
        _Pragma("unroll") for (int ks = 0; ks < 2; ks++) {                     \
            _Pragma("unroll") for (int ii = 0; ii < 4; ii++) {                 \
                _Pragma("unroll") for (int jj = 0; jj < 2; jj++) {             \
                    acc[(IH) * 4 + ii][(JH) * 2 + jj] =                        \
                        __builtin_amdgcn_mfma_f32_16x16x32_bf16(               \
                            af[ii][ks], bf[jj][ks],                            \
                            acc[(IH) * 4 + ii][(JH) * 2 + jj], 0, 0, 0);       \
                }                                                              \
            }                                                                  \
        }                                                                      \
        __builtin_amdgcn_s_setprio(0);                                         \
        if (VM) { asm volatile("s_waitcnt vmcnt(2)" ::: "memory"); }           \
        __builtin_amdgcn_s_barrier();                                          \
    } while (0)

    // ---- prologue: tile 0 fully + tile 1 Aq0,Aq2 (acts as "prev ph7") ----
#pragma unroll
    for (int q = 0; q < 4; q++) SA(0, q, 0);
#pragma unroll
    for (int q = 0; q < 4; q++) SB(0, q, 0);
    SA(1, 0, 1); SA(1, 2, 1);
    asm volatile("s_waitcnt vmcnt(2)" ::: "memory");   // tile 0 landed
    __builtin_amdgcn_s_barrier();

    f32x4 acc[8][4];
    f32x4 s_run[8];
#pragma unroll
    for (int i = 0; i < 8; i++) {
        s_run[i] = (f32x4){0.f, 0.f, 0.f, 0.f};
#pragma unroll
        for (int j = 0; j < 4; j++) acc[i][j] = (f32x4){0.f, 0.f, 0.f, 0.f};
    }
    bf16x8 af[4][2];

#pragma unroll 1
    for (int v0 = 0; v0 < 32; v0 += 2) {
        PHASE_(0, 0, 0, 1,
               SA(1, 1, v0 + 1); SA(1, 3, v0 + 1);
               SB(1, 0, v0 + 1); SB(1, 1, v0 + 1);
               SB(1, 2, v0 + 1); SB(1, 3, v0 + 1), 0);
        PHASE_(0, 0, 1, 0, (void)0, 0);
        PHASE_(0, 1, 0, 1, SA(0, 0, v0 + 2); SA(0, 2, v0 + 2), 0);
        PHASE_(0, 1, 1, 0, (void)0, 1);
        PHASE_(1, 0, 0, 1,
               SA(0, 1, v0 + 2); SA(0, 3, v0 + 2);
               SB(0, 0, v0 + 2); SB(0, 1, v0 + 2);
               SB(0, 2, v0 + 2); SB(0, 3, v0 + 2), 0);
        PHASE_(1, 0, 1, 0, (void)0, 0);
        PHASE_(1, 1, 0, 1, SA(1, 0, v0 + 3); SA(1, 2, v0 + 3), 0);
        PHASE_(1, 1, 1, 0, (void)0, 1);
        if ((v0 & 6) == 6) {
            // ct boundary: register-only exp flush (no barrier, no loads)
#pragma unroll
            for (int i = 0; i < 8; i++) {
#pragma unroll
                for (int rg = 0; rg < 4; rg++) {
                    float es = s_run[i][rg];
#pragma unroll
                    for (int j = 0; j < 4; j++)
                        es += __expf(fmaf(acc[i][j][rg], scale, -COFF));
                    s_run[i][rg] = es;
                }
#pragma unroll
                for (int j = 0; j < 4; j++)
                    acc[i][j] = (f32x4){0.f, 0.f, 0.f, 0.f};
            }
        }
    }

    asm volatile("s_waitcnt vmcnt(0)" ::: "memory");
    __syncthreads();

    // ---- epilogue: reduce s_run across ln, fold 4 wc-waves via LDS ----
    float* fred = (float*)lds;
#pragma unroll
    for (int i = 0; i < 8; i++) {
#pragma unroll
        for (int rg = 0; rg < 4; rg++) {
            float es = s_run[i][rg];
#pragma unroll
            for (int off = 8; off; off >>= 1) es += __shfl_xor(es, off);
            if (ln == 0)
                fred[(wr * 128 + i * 16 + lq * 4 + rg) * 4 + wc] = es;
        }
    }
    __syncthreads();
    if (tid < 256) {
        const float tot = fred[tid * 4] + fred[tid * 4 + 1]
                        + fred[tid * 4 + 2] + fred[tid * 4 + 3];
        ps[(size_t)(row0 + tid) * PSW + bcg] = tot;
    }
#undef SA
#undef SB
#undef PHASE_
}

// ---------------------------------------------------------------------------
// Kernel C: combine partials -> lse, per-row fp32 dot products, reduce.
// ---------------------------------------------------------------------------
__global__ __launch_bounds__(256) void k_finalize(
    const float* __restrict__ img, const float* __restrict__ txt,
    const int* __restrict__ labels, const float* __restrict__ scale_p,
    const float* __restrict__ Tsum, const int* __restrict__ counts,
    const float* __restrict__ ps,
    float* __restrict__ out)
{
    const float scale = scale_p[0];
    const int tid = threadIdx.x;
    const int lane = tid & 63;
    const int wave = tid >> 6;
    const int rowBase = blockIdx.x * 16 + wave * 4;
    float local = 0.f;
#pragma unroll
    for (int it = 0; it < 4; it++) {
        const int i = rowBase + it;
        const int lab = labels[i];
        float ds = 0.f, dt = 0.f;
        const float* ip = img + (size_t)i * DD;
        const float* tp = txt + (size_t)i * DD;
        const float* sp = Tsum + lab * DD;
#pragma unroll
        for (int k = lane; k < DD; k += 64) {
            const float a = ip[k];
            ds = fmaf(a, tp[k], ds);
            dt = fmaf(a, sp[k], dt);
        }
        float es = (lane < PSW) ? ps[(size_t)i * PSW + lane] : 0.f;
#pragma unroll
        for (int off = 32; off; off >>= 1) {
            ds += __shfl_xor(ds, off);
            dt += __shfl_xor(dt, off);
            es += __shfl_xor(es, off);
        }
        if (lane == 0) {
            const float lse = COFF + __logf(es);
            const int cnt = counts[lab] - 1;
            if (cnt > 0) {
                const float row_sum = scale * (dt - ds) - (float)cnt * lse;
                local += row_sum / (float)cnt;
            }
        }
    }
    __shared__ float red[4];
    if (lane == 0) red[wave] = local;
    __syncthreads();
    if (tid == 0) {
        const float t = red[0] + red[1] + red[2] + red[3];
        atomicAdd(out, -t / (float)NN);
    }
}

// ---------------------------------------------------------------------------
extern "C" void kernel_launch(void* const* d_in, const int* in_sizes, int n_in,
                              void* d_out, int out_size, void* d_ws, size_t ws_size,
                              hipStream_t stream)
{
    const float* img     = (const float*)d_in[0];
    const float* txt     = (const float*)d_in[1];
    const float* scale_p = (const float*)d_in[2];
    const int*   labels  = (const int*)d_in[3];
    float* out = (float*)d_out;

    char* ws = (char*)d_ws;
    float* ps    = (float*)(ws);                                  // 256 KB (8192 x 8)
    float* Tsum  = (float*)(ws + (1 << 18));                      // 16 KB
    int*   counts = (int*)(ws + (1 << 18) + NSRC * DD * 4);
    unsigned short* imgB = (unsigned short*)(ws + 2 * 1024 * 1024);   // 8 MB
    unsigned short* txtB = (unsigned short*)(ws + 10 * 1024 * 1024);  // 8 MB

    hipMemsetAsync(ws + (1 << 18), 0, NSRC * DD * 4 + 64, stream);  // Tsum+counts
    hipMemsetAsync(d_out, 0, 4, stream);                            // out

    k_prep<<<128 + (2 * NN * DD / 8) / 256, 256, 0, stream>>>(
        img, txt, labels, imgB, txtB, Tsum, counts);
    k_lse_mfma256<<<256, 512, 0, stream>>>(imgB, txtB, scale_p, ps);
    k_finalize<<<NN / 16, 256, 0, stream>>>(img, txt, labels, scale_p,
                                            Tsum, counts, ps, out);
}